// Round 1
// baseline (377.093 us; speedup 1.0000x reference)
//
#include <hip/hip_runtime.h>
#include <math.h>

#define Dm 1024
#define Hh 16
#define DHd 64
#define Ff 4096
#define Tt 2048
#define Bb 2

#define ATT_C2 0.18033688011112042f   // 0.125 * log2(e), folded into Q at QK GEMM

typedef __bf16 bf16_8 __attribute__((ext_vector_type(8)));
typedef __bf16 bf16x2 __attribute__((ext_vector_type(2)));
typedef __bf16 bf16x4 __attribute__((ext_vector_type(4)));
typedef float  f32x4  __attribute__((ext_vector_type(4)));

__device__ __forceinline__ unsigned short f2bf(float f) {
    unsigned int u = __float_as_uint(f);
    unsigned int r = (u + 0x7fffu + ((u >> 16) & 1u)) >> 16;   // RNE
    return (unsigned short)r;
}

// native packed f32->bf16 (gfx950 v_cvt_pk_bf16_f32), RNE — fallback to cast
__device__ __forceinline__ bf16x2 pkbf(float a, float b) {
#if __has_builtin(__builtin_amdgcn_cvt_pk_bf16_f32)
    return __builtin_amdgcn_cvt_pk_bf16_f32(a, b);
#else
    bf16x2 r; r[0] = (__bf16)a; r[1] = (__bf16)b; return r;
#endif
}
__device__ __forceinline__ bf16x4 pkbf4(float a, float b, float c, float d) {
    bf16x2 lo = pkbf(a, b), hi = pkbf(c, d);
    return __builtin_shufflevector(lo, hi, 0, 1, 2, 3);
}

__device__ __forceinline__ void gld_lds16(const void* g, void* l) {
    __builtin_amdgcn_global_load_lds(
        (const __attribute__((address_space(1))) void*)g,
        (__attribute__((address_space(3))) void*)l,
        16, 0, 0);
}

// ---------------------------------------------------------------------------
// One-shot preprocess: all fp32->bf16 weight/src conversions + mask bit-pack
// + QK bias concat, in a single dispatch.
// ---------------------------------------------------------------------------
__global__ __launch_bounds__(256) void preprocess_kernel(
    const float* __restrict__ q_w, const float* __restrict__ k_w,
    const float* __restrict__ v_w, const float* __restrict__ o_w,
    const float* __restrict__ l1_w, const float* __restrict__ l2_w,
    const float* __restrict__ src, const int* __restrict__ mask,
    const float* __restrict__ q_b, const float* __restrict__ k_b,
    unsigned short* __restrict__ qkw, unsigned short* __restrict__ vw16,
    unsigned short* __restrict__ ow,  unsigned short* __restrict__ l1w,
    unsigned short* __restrict__ l2w, unsigned short* __restrict__ srcb,
    unsigned* __restrict__ mbit, float* __restrict__ qkb)
{
    const int bid = blockIdx.x;
    const int tid = threadIdx.x;
    if (bid < 16384) {                      // fp32 -> bf16, float4 granules
        int i = bid * 256 + tid;
        const float* sp; unsigned short* dp; int off;
        if (i < 1048576) {
            if (i < 262144)      { sp = q_w; dp = qkw;           off = i; }
            else if (i < 524288) { sp = k_w; dp = qkw + 1048576; off = i - 262144; }
            else if (i < 786432) { sp = v_w; dp = vw16;          off = i - 524288; }
            else                 { sp = o_w; dp = ow;            off = i - 786432; }
        } else if (i < 2097152)  { sp = l1_w; dp = l1w;          off = i - 1048576; }
        else if (i < 3145728)    { sp = l2_w; dp = l2w;          off = i - 2097152; }
        else                     { sp = src;  dp = srcb;         off = i - 3145728; }
        float4 v = ((const float4*)sp)[off];
        ((bf16x4*)dp)[off] = pkbf4(v.x, v.y, v.z, v.w);
    } else if (bid < 16896) {               // mask [2048][2048] -> bits
        int w = (bid - 16384) * 256 + tid;
        const int* p = mask + (size_t)w * 32;
        unsigned bits = 0;
        #pragma unroll
        for (int j = 0; j < 8; ++j) {
            int4 v = ((const int4*)p)[j];
            bits |= (v.x != 0 ? 1u : 0u) << (j * 4 + 0);
            bits |= (v.y != 0 ? 1u : 0u) << (j * 4 + 1);
            bits |= (v.z != 0 ? 1u : 0u) << (j * 4 + 2);
            bits |= (v.w != 0 ? 1u : 0u) << (j * 4 + 3);
        }
        mbit[w] = bits;
    } else {                                // QK bias concat (2048)
        int i = (bid - 16896) * 256 + tid;
        qkb[i] = (i < 1024) ? q_b[i] : k_b[i - 1024];
    }
}

// ---------------------------------------------------------------------------
// bf16 MFMA GEMM, 128x128 tile, BK=64. C = A @ W^T + bias. LDS 32 KB.
// Frag reads XOR-chunk swizzled. Split-K via gridDim.z: z=0 -> C (+bias),
// z=1 -> C2 (no bias); partials summed downstream.
// ---------------------------------------------------------------------------
template<int RELU, int BF16OUT>
__global__ __launch_bounds__(256) void gemm_bf16_kernel(
    const unsigned short* __restrict__ A, const unsigned short* __restrict__ W,
    const float* __restrict__ bias, void* __restrict__ C, void* __restrict__ C2,
    int M, int N, int K, int ldc, int ksub)
{
    __shared__ __bf16 As[128][64];   // 16 KB
    __shared__ __bf16 Bs[128][64];   // 16 KB
    const int tid  = threadIdx.x;
    const int lane = tid & 63;
    const int wave = tid >> 6;
    const int m0 = blockIdx.y * 128;
    const int n0 = blockIdx.x * 128;
    const int lr8 = lane >> 3;            // row within 8-row segment
    const int gch = (lane & 7) ^ lr8;     // swizzled global chunk
    const int wm = (wave & 1) * 64;
    const int wn = (wave >> 1) * 64;
    const int quad = lane >> 4;
    const int lm = lane & 15;
    const int z  = blockIdx.z;
    const int kstart = z * ksub;
    void* Cz = (z == 0) ? C : C2;

    f32x4 acc[4][4];
    #pragma unroll
    for (int i = 0; i < 4; i++)
        #pragma unroll
        for (int j = 0; j < 4; j++) {
            acc[i][j][0] = 0.f; acc[i][j][1] = 0.f;
            acc[i][j][2] = 0.f; acc[i][j][3] = 0.f;
        }

    for (int k0 = kstart; k0 < kstart + ksub; k0 += 64) {
        __syncthreads();
        #pragma unroll
        for (int i = 0; i < 4; i++) {
            int seg = wave * 4 + i;
            int r = seg * 8 + lr8;
            gld_lds16(A + (size_t)(m0 + r) * K + k0 + gch * 8, &As[seg * 8][0]);
            gld_lds16(W + (size_t)(n0 + r) * K + k0 + gch * 8, &Bs[seg * 8][0]);
        }
        __syncthreads();
        #pragma unroll
        for (int kh = 0; kh < 2; kh++) {
            bf16_8 af[4], bfr[4];
            #pragma unroll
            for (int t = 0; t < 4; t++) {
                int ch = (kh * 4 + quad) ^ (lm & 7);
                af[t]  = *(const bf16_8*)&As[wm + t * 16 + lm][ch * 8];
                bfr[t] = *(const bf16_8*)&Bs[wn + t * 16 + lm][ch * 8];
            }
            #pragma unroll
            for (int i = 0; i < 4; i++)
                #pragma unroll
                for (int j = 0; j < 4; j++)
                    acc[i][j] = __builtin_amdgcn_mfma_f32_16x16x32_bf16(
                        af[i], bfr[j], acc[i][j], 0, 0, 0);
        }
    }

    float bvc[4];
    #pragma unroll
    for (int j = 0; j < 4; j++)
        bvc[j] = (z == 0) ? bias[n0 + wn + j * 16 + lm] : 0.f;

    #pragma unroll
    for (int i = 0; i < 4; i++)
        #pragma unroll
        for (int j = 0; j < 4; j++) {
            int col = n0 + wn + j * 16 + lm;
            #pragma unroll
            for (int r = 0; r < 4; r++) {
                int row = m0 + wm + i * 16 + quad * 4 + r;
                float v = acc[i][j][r] + bvc[j];
                if (RELU) v = fmaxf(v, 0.f);
                if (BF16OUT)
                    ((unsigned short*)Cz)[(size_t)row * ldc + col] = f2bf(v);
                else
                    ((float*)Cz)[(size_t)row * ldc + col] = v;
            }
        }
}

// ---------------------------------------------------------------------------
// FFN1 GEMM: hb[4096,4096] = relu(x1b[4096,1024] @ l1w[4096,1024]^T + l1_b).
// 256x128 tile, BK=64, LDS 48 KB, acc 4x8 per wave. 512 blocks = 2/CU exact.
// Staging bytes/MFMA 192 vs 256 for the 128^2 tile; MFMA:ds_read 2.7 vs 2.0.
// ---------------------------------------------------------------------------
__global__ __launch_bounds__(256, 2) void gemm_ffn1_kernel(
    const unsigned short* __restrict__ A, const unsigned short* __restrict__ W,
    const float* __restrict__ bias, unsigned short* __restrict__ C)
{
    __shared__ __bf16 As[256][64];   // 32 KB
    __shared__ __bf16 Bs[128][64];   // 16 KB
    const int tid  = threadIdx.x;
    const int lane = tid & 63;
    const int wave = tid >> 6;
    const int m0 = blockIdx.y * 256;
    const int n0 = blockIdx.x * 128;
    const int lr8 = lane >> 3;
    const int gch = (lane & 7) ^ lr8;
    const int quad = lane >> 4;
    const int lm = lane & 15;

    f32x4 acc[4][8];
    #pragma unroll
    for (int i = 0; i < 4; i++)
        #pragma unroll
        for (int j = 0; j < 8; j++) {
            acc[i][j][0] = 0.f; acc[i][j][1] = 0.f;
            acc[i][j][2] = 0.f; acc[i][j][3] = 0.f;
        }

    for (int k0 = 0; k0 < 1024; k0 += 64) {
        __syncthreads();
        #pragma unroll
        for (int i = 0; i < 8; i++) {          // A: 8 segments/wave
            int seg = wave * 8 + i;
            int r = seg * 8 + lr8;
            gld_lds16(A + (size_t)(m0 + r) * 1024 + k0 + gch * 8, &As[seg * 8][0]);
        }
        #pragma unroll
        for (int i = 0; i < 4; i++) {          // B: 4 segments/wave
            int seg = wave * 4 + i;
            int r = seg * 8 + lr8;
            gld_lds16(W + (size_t)(n0 + r) * 1024 + k0 + gch * 8, &Bs[seg * 8][0]);
        }
        __syncthreads();
        #pragma unroll
        for (int kh = 0; kh < 2; kh++) {
            const int ch = (kh * 4 + quad) ^ (lm & 7);
            bf16_8 af[4], bfr[8];
            #pragma unroll
            for (int t = 0; t < 4; t++)
                af[t] = *(const bf16_8*)&As[wave * 64 + t * 16 + lm][ch * 8];
            #pragma unroll
            for (int j = 0; j < 8; j++)
                bfr[j] = *(const bf16_8*)&Bs[j * 16 + lm][ch * 8];
            #pragma unroll
            for (int i = 0; i < 4; i++)
                #pragma unroll
                for (int j = 0; j < 8; j++)
                    acc[i][j] = __builtin_amdgcn_mfma_f32_16x16x32_bf16(
                        af[i], bfr[j], acc[i][j], 0, 0, 0);
        }
    }

    float bv[8];
    #pragma unroll
    for (int j = 0; j < 8; j++) bv[j] = bias[n0 + j * 16 + lm];

    #pragma unroll
    for (int i = 0; i < 4; i++)
        #pragma unroll
        for (int j = 0; j < 8; j++) {
            int col = n0 + j * 16 + lm;
            #pragma unroll
            for (int r = 0; r < 4; r++) {
                int row = m0 + wave * 64 + i * 16 + quad * 4 + r;
                float v = fmaxf(acc[i][j][r] + bv[j], 0.f);
                C[(size_t)row * Ff + col] = f2bf(v);
            }
        }
}

// ---------------------------------------------------------------------------
// Merged QK + Vt GEMM (768 blocks), BK=64.
// blocks [0,512):   qk16[4096,2048] = srcb @ [q_w;k_w]^T + qkb, Q cols ×ATT_C2
// blocks [512,768): vtf [1024,4096] = vw16 @ srcb^T + v_b (row bias)
// ---------------------------------------------------------------------------
__global__ __launch_bounds__(256) void gemm_qkvt_kernel(
    const unsigned short* __restrict__ srcb, const unsigned short* __restrict__ qkw,
    const unsigned short* __restrict__ vw16, const float* __restrict__ qkb,
    const float* __restrict__ v_b,
    unsigned short* __restrict__ qk16, unsigned short* __restrict__ vtf)
{
    const int bid = blockIdx.x;
    const unsigned short *A, *W;
    const float* bias;
    unsigned short* C;
    int m0, n0, ldc;
    bool qscale, rowbias;
    if (bid < 512) {
        A = srcb; W = qkw; bias = qkb; C = qk16;
        n0 = (bid & 15) * 128; m0 = (bid >> 4) * 128;
        ldc = 2048; qscale = true; rowbias = false;
    } else {
        int b2 = bid - 512;
        A = vw16; W = srcb; bias = v_b; C = vtf;
        n0 = (b2 & 31) * 128; m0 = (b2 >> 5) * 128;
        ldc = 4096; qscale = false; rowbias = true;
    }
    const int K = 1024;

    __shared__ __bf16 As[128][64];
    __shared__ __bf16 Bs[128][64];
    const int tid  = threadIdx.x;
    const int lane = tid & 63;
    const int wave = tid >> 6;
    const int lr8 = lane >> 3;
    const int gch = (lane & 7) ^ lr8;
    const int wm = (wave & 1) * 64;
    const int wn = (wave >> 1) * 64;
    const int quad = lane >> 4;
    const int lm = lane & 15;

    f32x4 acc[4][4];
    #pragma unroll
    for (int i = 0; i < 4; i++)
        #pragma unroll
        for (int j = 0; j < 4; j++) {
            acc[i][j][0] = 0.f; acc[i][j][1] = 0.f;
            acc[i][j][2] = 0.f; acc[i][j][3] = 0.f;
        }

    for (int k0 = 0; k0 < K; k0 += 64) {
        __syncthreads();
        #pragma unroll
        for (int i = 0; i < 4; i++) {
            int seg = wave * 4 + i;
            int r = seg * 8 + lr8;
            gld_lds16(A + (size_t)(m0 + r) * K + k0 + gch * 8, &As[seg * 8][0]);
            gld_lds16(W + (size_t)(n0 + r) * K + k0 + gch * 8, &Bs[seg * 8][0]);
        }
        __syncthreads();
        #pragma unroll
        for (int kh = 0; kh < 2; kh++) {
            bf16_8 af[4], bfr[4];
            #pragma unroll
            for (int t = 0; t < 4; t++) {
                int ch = (kh * 4 + quad) ^ (lm & 7);
                af[t]  = *(const bf16_8*)&As[wm + t * 16 + lm][ch * 8];
                bfr[t] = *(const bf16_8*)&Bs[wn + t * 16 + lm][ch * 8];
            }
            #pragma unroll
            for (int i = 0; i < 4; i++)
                #pragma unroll
                for (int j = 0; j < 4; j++)
                    acc[i][j] = __builtin_amdgcn_mfma_f32_16x16x32_bf16(
                        af[i], bfr[j], acc[i][j], 0, 0, 0);
        }
    }

    float bvc[4];
    float brr[4][4];
    if (!rowbias) {
        #pragma unroll
        for (int j = 0; j < 4; j++) bvc[j] = bias[n0 + wn + j * 16 + lm];
    } else {
        #pragma unroll
        for (int i = 0; i < 4; i++) {
            float4 t4 = *(const float4*)&bias[m0 + wm + i * 16 + quad * 4];
            brr[i][0] = t4.x; brr[i][1] = t4.y; brr[i][2] = t4.z; brr[i][3] = t4.w;
        }
    }

    #pragma unroll
    for (int i = 0; i < 4; i++)
        #pragma unroll
        for (int j = 0; j < 4; j++) {
            int col = n0 + wn + j * 16 + lm;
            #pragma unroll
            for (int r = 0; r < 4; r++) {
                int row = m0 + wm + i * 16 + quad * 4 + r;
                float v = acc[i][j][r] + (rowbias ? brr[i][r] : bvc[j]);
                if (qscale && col < 1024) v *= ATT_C2;
                C[(size_t)row * ldc + col] = f2bf(v);
            }
        }
}

// ---------------------------------------------------------------------------
// MFMA flash attention, static softmax, single dispatch (512 blocks).
// Block = (b,h,128 q), 8 waves x 16 t (was 4x32): same grid, 512 threads,
// Ps shrinks to [8][16*64] so LDS stays 48 KB -> 2 blocks/CU x 8 waves =
// 16 waves/CU (50% occupancy vs 25%). Kernel is latency-bound (MfmaUtil 22%,
// VALUBusy 42%, HBM 15%) -> doubling resident waves hides the exp2/softmax
// VALU chain and LDS latencies. S^T (A=K,B=Q) puts t on lane&15. Row-sum l
// via MFMA against ones (layout-aligned with O). In-kernel normalize, bf16.
// __launch_bounds__(512,4) pins VGPR<=128 for 4 waves/SIMD.
// ---------------------------------------------------------------------------
__global__ __launch_bounds__(512, 4) void attn_mfma_kernel(
    const unsigned short* __restrict__ qk,
    const unsigned short* __restrict__ vt,
    const unsigned* __restrict__ mb,
    unsigned short* __restrict__ out)
{
    __shared__ __bf16 Ks[128 * 64];      // 16 KB
    __shared__ __bf16 Vt[64 * 128];      // 16 KB
    __shared__ __bf16 Ps[8][16 * 64];    // 16 KB, per-wave

    const int tid  = threadIdx.x;
    const int lane = tid & 63;
    const int wave = tid >> 6;           // 0..7
    const int c    = lane & 15;
    const int quad = lane >> 4;
    const int bh = blockIdx.y;
    const int b = bh >> 4, h = bh & 15;
    const int t0 = blockIdx.x * 128;
    const int tw = t0 + wave * 16;       // 16 q-rows per wave

    bf16_8 qf[2];
    #pragma unroll
    for (int ks = 0; ks < 2; ++ks)
        qf[ks] = *(const bf16_8*)(qk +
            (size_t)(b * Tt + tw + c) * 2048 +
            h * DHd + quad * 8 + ks * 32);

    f32x4 oacc[4];
    f32x4 ol;
    ol[0] = 0.f; ol[1] = 0.f; ol[2] = 0.f; ol[3] = 0.f;
    #pragma unroll
    for (int dt = 0; dt < 4; ++dt) {
        oacc[dt][0] = 0.f; oacc[dt][1] = 0.f;
        oacc[dt][2] = 0.f; oacc[dt][3] = 0.f;
    }
    bf16_8 vone;
    {
        __bf16 one = (__bf16)1.0f;
        #pragma unroll
        for (int j = 0; j < 8; ++j) vone[j] = one;
    }

    const int krow8 = lane >> 3;
    const int kj    = (lane & 7) ^ krow8;    // staging swizzle
    const int vr4   = lane >> 4;

    for (int st16 = 0; st16 < 16; ++st16) {
        const int s0 = st16 * 128;
        __syncthreads();

        // ---- stage K [128 s][64 d] and Vt [64 d][128 s], swizzled ----
        #pragma unroll
        for (int i = 0; i < 2; ++i) {
            int ci = wave * 2 + i;           // 0..15
            {
                int r = 8 * ci + krow8;
                const unsigned short* g = qk +
                    (size_t)(b * Tt + s0 + r) * 2048 + 1024 + h * DHd + kj * 8;
                gld_lds16(g, &Ks[ci * 512]);
            }
            {
                int d = 4 * ci + vr4;
                int jj = (lane & 15) ^ (d & 7);
                const unsigned short* g = vt +
                    (size_t)(h * DHd + d) * 4096 + b * Tt + s0 + jj * 8;
                gld_lds16(g, &Vt[ci * 512]);
            }
        }

        unsigned mwv[4];
        #pragma unroll
        for (int sp = 0; sp < 4; ++sp)
            mwv[sp] = mb[(size_t)(tw + c) * 64 + (s0 >> 5) + sp];

        __syncthreads();

        #pragma unroll
        for (int half = 0; half < 2; ++half) {
            // ---- S^T + exp + P write for this 64-s half ----
            #pragma unroll
            for (int s8l = 0; s8l < 4; ++s8l) {
                const int s8 = half * 4 + s8l;
                bf16_8 kf0 = *(const bf16_8*)&Ks[((s8 * 16 + c) * 8 + ((quad + 0) ^ (c & 7))) * 8];
                bf16_8 kf1 = *(const bf16_8*)&Ks[((s8 * 16 + c) * 8 + ((quad + 4) ^ (c & 7))) * 8];
                f32x4 zr; zr[0] = 0.f; zr[1] = 0.f; zr[2] = 0.f; zr[3] = 0.f;
                zr = __builtin_amdgcn_mfma_f32_16x16x32_bf16(kf0, qf[0], zr, 0, 0, 0);
                f32x4 sv = __builtin_amdgcn_mfma_f32_16x16x32_bf16(kf1, qf[1], zr, 0, 0, 0);
                unsigned mword = mwv[s8 >> 1];
                int bp = (s8 & 1) * 16 + quad * 4;
                float p[4];
                #pragma unroll
                for (int r = 0; r < 4; ++r) {
                    int bit = (mword >> (bp + r)) & 1;
                    float x = bit ? -1e30f : sv[r];
                    p[r] = __builtin_amdgcn_exp2f(x);   // masked -> 0
                }
                bf16x4 pk4v = pkbf4(p[0], p[1], p[2], p[3]);
                int ch = (s8l * 2 + (quad >> 1)) ^ (c & 7);
                *(bf16x4*)&Ps[wave][c * 64 + ch * 8 + (quad & 1) * 4] = pk4v;
            }
            // ---- PV + l for this half (same-wave Ps, in-order DS pipe) ----
            #pragma unroll
            for (int ks = 0; ks < 2; ++ks) {
                bf16_8 pa, vf[4];
                {
                    int ch = (ks * 4 + quad) ^ (c & 7);
                    pa = *(const bf16_8*)&Ps[wave][c * 64 + ch * 8];
                }
                #pragma unroll
                for (int dt = 0; dt < 4; ++dt) {
                    int sc = half * 8 + ks * 4 + quad;
                    int d = dt * 16 + c;
                    vf[dt] = *(const bf16_8*)&Vt[(d * 16 + (sc ^ (c & 7))) * 8];
                }
                #pragma unroll
                for (int dt = 0; dt < 4; ++dt)
                    oacc[dt] = __builtin_amdgcn_mfma_f32_16x16x32_bf16(
                        pa, vf[dt], oacc[dt], 0, 0, 0);
                ol = __builtin_amdgcn_mfma_f32_16x16x32_bf16(
                    pa, vone, ol, 0, 0, 0);
            }
        }
    }

    // ---- epilogue: O / l (all-masked row: l=0 -> 0), store bf16 ----
    #pragma unroll
    for (int r = 0; r < 4; ++r) {
        float l = ol[r];
        float inv = (l > 0.f) ? 1.f / l : 0.f;
        int row = b * Tt + tw + quad * 4 + r;
        #pragma unroll
        for (int dt = 0; dt < 4; ++dt)
            out[(size_t)row * Dm + h * DHd + dt * 16 + c] =
                f2bf(oacc[dt][r] * inv);
    }
}

// ---------------------------------------------------------------------------
// out = LayerNorm(base + alpha*(d0[+d1]))*scale + bias.
// BASEBF: base is bf16. OUTF32 -> out fp32; OUTBF -> out_bf bf16.
// ---------------------------------------------------------------------------
template<int NPARTS, int BASEBF, int OUTF32, int OUTBF>
__global__ __launch_bounds__(256) void residual_ln_kernel(
    const void* __restrict__ base, const float* __restrict__ d0,
    const float* __restrict__ d1,
    const float* __restrict__ alpha_p, const float* __restrict__ scale,
    const float* __restrict__ bias, float* __restrict__ out,
    unsigned short* __restrict__ out_bf)
{
    const int row = blockIdx.x;
    const int tid = threadIdx.x;
    const float alpha = alpha_p[0];
    float4 xb;
    if (BASEBF) {
        bf16x4 bb = ((const bf16x4*)((const unsigned short*)base + (size_t)row * Dm))[tid];
        xb.x = (float)bb[0]; xb.y = (float)bb[1]; xb.z = (float)bb[2]; xb.w = (float)bb[3];
    } else {
        xb = ((const float4*)((const float*)base + (size_t)row * Dm))[tid];
    }
    float4 xd = ((const float4*)(d0 + (size_t)row * Dm))[tid];
    if (NPARTS == 2) {
        float4 x2 = ((const float4*)(d1 + (size_t)row * Dm))[tid];
        xd.x += x2.x; xd.y += x2.y; xd.z += x2.z; xd.w += x2.w;
    }
    float4 x;
    x.x = xb.x + alpha * xd.x;
    x.y = xb.y + alpha * xd.y;
    x.z = xb.z + alpha * xd.z;
    x.w = xb.w + alpha * xd.w;
    float s  = x.x + x.y + x.z + x.w;
    float sq = x.x*x.x + x.y*x.y + x.z*x.z + x.w*x.w;
    #pragma unroll
    for (int off = 32; off > 0; off >>= 1) {
        s  += __shfl_down(s, off, 64);
        sq += __shfl_down(sq, off, 64);
    }
    __shared__ float red[8];
    const int w = tid >> 6;
    if ((tid & 63) == 0) { red[w] = s; red[4 + w] = sq; }
    __syncthreads();
    s  = red[0] + red[1] + red[2] + red[3];
    sq = red[4] + red[5] + red[6] + red[7];
    const float mu  = s * (1.f / Dm);
    const float var = sq * (1.f / Dm) - mu * mu;
    const float r   = rsqrtf(var + 1e-5f);
    float4 sc = ((const float4*)scale)[tid];
    float4 bi = ((const float4*)bias)[tid];
    float4 o;
    o.x = (x.x - mu) * r * sc.x + bi.x;
    o.y = (x.y - mu) * r * sc.y + bi.y;
    o.z = (x.z - mu) * r * sc.z + bi.z;
    o.w = (x.w - mu) * r * sc.w + bi.w;
    if (OUTF32)
        ((float4*)(out + (size_t)row * Dm))[tid] = o;
    if (OUTBF)
        ((bf16x4*)(out_bf + (size_t)row * Dm))[tid] = pkbf4(o.x, o.y, o.z, o.w);
}

// ---------------------------------------------------------------------------
extern "C" void kernel_launch(void* const* d_in, const int* in_sizes, int n_in,
                              void* d_out, int out_size, void* d_ws, size_t ws_size,
                              hipStream_t stream)
{
    (void)in_sizes; (void)n_in; (void)out_size; (void)ws_size;
    const float* src  = (const float*)d_in[0];
    const int*   mask = (const int*)  d_in[1];
    const float* q_w  = (const float*)d_in[2];
    const float* q_b  = (const float*)d_in[3];
    const float* k_w  = (const float*)d_in[4];
    const float* k_b  = (const float*)d_in[5];
    const float* v_w  = (const float*)d_in[6];
    const float* v_b  = (const float*)d_in[7];
    const float* o_w  = (const float*)d_in[8];
    const float* o_b  = (const float*)d_in[9];
    const float* l1_w = (const float*)d_in[10];
    const float* l1_b = (const float*)d_in[11];
    const float* l2_w = (const float*)d_in[12];
    const float* l2_b = (const float*)d_in[13];
    const float* n1_s = (const float*)d_in[14];
    const float* n1_b = (const float*)d_in[15];
    const float* n2_s = (const float*)d_in[16];
    const float* n2_b = (const float*)d_in[17];
    const float* a_attn = (const float*)d_in[18];
    const float* a_ff   = (const float*)d_in[19];

    // ---- workspace layout (96 MB), lifetimes annotated ----
    const size_t MB = 1024 * 1024;
    char* w = (char*)d_ws;
    unsigned short* qkw  = (unsigned short*)(w + 0);        // [ 0, 4)   -> qkvt
    unsigned short* vw16 = (unsigned short*)(w + 4  * MB);  // [ 4, 6)   -> qkvt
    unsigned short* ow   = (unsigned short*)(w + 6  * MB);  // [ 6, 8)   -> O gemm
    unsigned short* l1w  = (unsigned short*)(w + 8  * MB);  // [ 8,16)   -> FFN1
    unsigned short* l2w  = (unsigned short*)(w + 16 * MB);  // [16,24)   -> FFN2
    unsigned short* srcb = (unsigned short*)(w + 24 * MB);  // [24,32)   -> qkvt
    unsigned short* qk16 = (unsigned short*)(w + 32 * MB);  // [32,48)   -> attn
    unsigned short* vtf  = (unsigned short*)(w + 48 * MB);  // [48,56)   -> attn
    unsigned*       mbit = (unsigned*)      (w + 56 * MB);            // 512 KB
    float*          qkb  = (float*)         (w + 56 * MB + 524288);   // 8 KB
    // post-attention reuse:
    unsigned short* atb  = (unsigned short*)(w + 24 * MB);  // [24,32)   -> O gemm (srcb dead)
    float*          o0   = (float*)         (w + 58 * MB);  // [58,74)   -> LN1
    float*          o1   = (float*)         (w + 74 * MB);  // [74,90)   -> LN1
    unsigned short* x1b  = (unsigned short*)(w + 48 * MB);  // [48,56)   -> FFN1+LN2 (vtf dead)
    unsigned short* hb   = (unsigned short*)(w + 58 * MB);  // [58,90)   -> FFN2 (o0/o1 dead)
    float*          fp0  = (float*)         (w + 0);        // [ 0,16)   -> LN2 (qkw/vw16/ow dead)
    float*          fp1  = (float*)         (w + 32 * MB);  // [32,48)   -> LN2 (qk16 dead)

    const int MR = Bb * Tt;   // 4096
    dim3 blk(256);

    // 1) conversions + mask pack + bias concat
    preprocess_kernel<<<dim3(16904), blk, 0, stream>>>(
        q_w, k_w, v_w, o_w, l1_w, l2_w, src, mask, q_b, k_b,
        qkw, vw16, ow, l1w, l2w, srcb, mbit, qkb);
    // 2) merged QK + Vt GEMMs
    gemm_qkvt_kernel<<<dim3(768), blk, 0, stream>>>(
        srcb, qkw, vw16, qkb, v_b, qk16, vtf);
    // 3) MFMA flash attention -> atb bf16 (single dispatch, full s sweep)
    attn_mfma_kernel<<<dim3(16, 32), dim3(512), 0, stream>>>(qk16, vtf, mbit, atb);
    // 4) O projection, split-K=2 -> two fp32 partials
    gemm_bf16_kernel<0, 0><<<dim3(8, 32, 2), blk, 0, stream>>>(
        atb, ow, o_b, o0, o1, MR, Dm, Dm, Dm, 512);
    // 5) LN1 (sums O partials) -> x1b bf16 only
    residual_ln_kernel<2, 0, 0, 1><<<dim3(MR), blk, 0, stream>>>(
        src, o0, o1, a_attn, n1_s, n1_b, nullptr, x1b);
    // 6) FFN1 + ReLU -> bf16 hidden, 256x128 tile
    gemm_ffn1_kernel<<<dim3(32, 16), blk, 0, stream>>>(x1b, l1w, l1_b, hb);
    // 7) FFN2, split-K=2 -> two fp32 partials
    gemm_bf16_kernel<0, 0><<<dim3(8, 32, 2), blk, 0, stream>>>(
        hb, l2w, l2_b, fp0, fp1, MR, Dm, Ff, Dm, Ff / 2);
    // 8) LN2 (bf16 base x1b; sums FFN2 partials) -> final fp32 output
    residual_ln_kernel<2, 1, 1, 0><<<dim3(MR), blk, 0, stream>>>(
        x1b, fp0, fp1, a_ff, n2_s, n2_b, (float*)d_out, nullptr);
}

// Round 2
// 370.314 us; speedup vs baseline: 1.0183x; 1.0183x over previous
//
#include <hip/hip_runtime.h>
#include <math.h>

#define Dm 1024
#define Hh 16
#define DHd 64
#define Ff 4096
#define Tt 2048
#define Bb 2

#define ATT_C2 0.18033688011112042f   // 0.125 * log2(e), folded into Q at QK GEMM

typedef __bf16 bf16_8 __attribute__((ext_vector_type(8)));
typedef __bf16 bf16x2 __attribute__((ext_vector_type(2)));
typedef __bf16 bf16x4 __attribute__((ext_vector_type(4)));
typedef float  f32x4  __attribute__((ext_vector_type(4)));
typedef float  f32x16 __attribute__((ext_vector_type(16)));
typedef unsigned int u32x4 __attribute__((ext_vector_type(4)));

__device__ __forceinline__ unsigned short f2bf(float f) {
    unsigned int u = __float_as_uint(f);
    unsigned int r = (u + 0x7fffu + ((u >> 16) & 1u)) >> 16;   // RNE
    return (unsigned short)r;
}

// native packed f32->bf16 (gfx950 v_cvt_pk_bf16_f32), RNE — fallback to cast
__device__ __forceinline__ bf16x2 pkbf(float a, float b) {
#if __has_builtin(__builtin_amdgcn_cvt_pk_bf16_f32)
    return __builtin_amdgcn_cvt_pk_bf16_f32(a, b);
#else
    bf16x2 r; r[0] = (__bf16)a; r[1] = (__bf16)b; return r;
#endif
}
__device__ __forceinline__ bf16x4 pkbf4(float a, float b, float c, float d) {
    bf16x2 lo = pkbf(a, b), hi = pkbf(c, d);
    return __builtin_shufflevector(lo, hi, 0, 1, 2, 3);
}

// v_permlane32_swap_b32: swaps upper 32 lanes of a with lower 32 lanes of b.
// After call: a = {a.lo, b.lo_from_partner}, b = {a.hi_to_partner, b.hi}.
// For lane l<32: a'=a[l], b'=a[l+32]; for l>=32: a'=b[l-32], b'=b[l].
__device__ __forceinline__ void plswap32(unsigned &a, unsigned &b) {
#if __has_builtin(__builtin_amdgcn_permlane32_swap)
    auto r = __builtin_amdgcn_permlane32_swap((int)a, (int)b, false, false);
    a = (unsigned)r[0]; b = (unsigned)r[1];
#else
    asm volatile("v_permlane32_swap_b32 %0, %1" : "+v"(a), "+v"(b));
#endif
}

__device__ __forceinline__ void gld_lds16(const void* g, void* l) {
    __builtin_amdgcn_global_load_lds(
        (const __attribute__((address_space(1))) void*)g,
        (__attribute__((address_space(3))) void*)l,
        16, 0, 0);
}

// ---------------------------------------------------------------------------
// One-shot preprocess: all fp32->bf16 weight/src conversions + mask bit-pack
// + QK bias concat, in a single dispatch.
// ---------------------------------------------------------------------------
__global__ __launch_bounds__(256) void preprocess_kernel(
    const float* __restrict__ q_w, const float* __restrict__ k_w,
    const float* __restrict__ v_w, const float* __restrict__ o_w,
    const float* __restrict__ l1_w, const float* __restrict__ l2_w,
    const float* __restrict__ src, const int* __restrict__ mask,
    const float* __restrict__ q_b, const float* __restrict__ k_b,
    unsigned short* __restrict__ qkw, unsigned short* __restrict__ vw16,
    unsigned short* __restrict__ ow,  unsigned short* __restrict__ l1w,
    unsigned short* __restrict__ l2w, unsigned short* __restrict__ srcb,
    unsigned* __restrict__ mbit, float* __restrict__ qkb)
{
    const int bid = blockIdx.x;
    const int tid = threadIdx.x;
    if (bid < 16384) {                      // fp32 -> bf16, float4 granules
        int i = bid * 256 + tid;
        const float* sp; unsigned short* dp; int off;
        if (i < 1048576) {
            if (i < 262144)      { sp = q_w; dp = qkw;           off = i; }
            else if (i < 524288) { sp = k_w; dp = qkw + 1048576; off = i - 262144; }
            else if (i < 786432) { sp = v_w; dp = vw16;          off = i - 524288; }
            else                 { sp = o_w; dp = ow;            off = i - 786432; }
        } else if (i < 2097152)  { sp = l1_w; dp = l1w;          off = i - 1048576; }
        else if (i < 3145728)    { sp = l2_w; dp = l2w;          off = i - 2097152; }
        else                     { sp = src;  dp = srcb;         off = i - 3145728; }
        float4 v = ((const float4*)sp)[off];
        ((bf16x4*)dp)[off] = pkbf4(v.x, v.y, v.z, v.w);
    } else if (bid < 16896) {               // mask [2048][2048] -> bits
        int w = (bid - 16384) * 256 + tid;
        const int* p = mask + (size_t)w * 32;
        unsigned bits = 0;
        #pragma unroll
        for (int j = 0; j < 8; ++j) {
            int4 v = ((const int4*)p)[j];
            bits |= (v.x != 0 ? 1u : 0u) << (j * 4 + 0);
            bits |= (v.y != 0 ? 1u : 0u) << (j * 4 + 1);
            bits |= (v.z != 0 ? 1u : 0u) << (j * 4 + 2);
            bits |= (v.w != 0 ? 1u : 0u) << (j * 4 + 3);
        }
        mbit[w] = bits;
    } else {                                // QK bias concat (2048)
        int i = (bid - 16896) * 256 + tid;
        qkb[i] = (i < 1024) ? q_b[i] : k_b[i - 1024];
    }
}

// ---------------------------------------------------------------------------
// bf16 MFMA GEMM, 128x128 tile, BK=64. C = A @ W^T + bias. LDS 32 KB.
// Frag reads XOR-chunk swizzled. Split-K via gridDim.z: z=0 -> C (+bias),
// z=1 -> C2 (no bias); partials summed downstream.
// ---------------------------------------------------------------------------
template<int RELU, int BF16OUT>
__global__ __launch_bounds__(256) void gemm_bf16_kernel(
    const unsigned short* __restrict__ A, const unsigned short* __restrict__ W,
    const float* __restrict__ bias, void* __restrict__ C, void* __restrict__ C2,
    int M, int N, int K, int ldc, int ksub)
{
    __shared__ __bf16 As[128][64];   // 16 KB
    __shared__ __bf16 Bs[128][64];   // 16 KB
    const int tid  = threadIdx.x;
    const int lane = tid & 63;
    const int wave = tid >> 6;
    const int m0 = blockIdx.y * 128;
    const int n0 = blockIdx.x * 128;
    const int lr8 = lane >> 3;            // row within 8-row segment
    const int gch = (lane & 7) ^ lr8;     // swizzled global chunk
    const int wm = (wave & 1) * 64;
    const int wn = (wave >> 1) * 64;
    const int quad = lane >> 4;
    const int lm = lane & 15;
    const int z  = blockIdx.z;
    const int kstart = z * ksub;
    void* Cz = (z == 0) ? C : C2;

    f32x4 acc[4][4];
    #pragma unroll
    for (int i = 0; i < 4; i++)
        #pragma unroll
        for (int j = 0; j < 4; j++) {
            acc[i][j][0] = 0.f; acc[i][j][1] = 0.f;
            acc[i][j][2] = 0.f; acc[i][j][3] = 0.f;
        }

    for (int k0 = kstart; k0 < kstart + ksub; k0 += 64) {
        __syncthreads();
        #pragma unroll
        for (int i = 0; i < 4; i++) {
            int seg = wave * 4 + i;
            int r = seg * 8 + lr8;
            gld_lds16(A + (size_t)(m0 + r) * K + k0 + gch * 8, &As[seg * 8][0]);
            gld_lds16(W + (size_t)(n0 + r) * K + k0 + gch * 8, &Bs[seg * 8][0]);
        }
        __syncthreads();
        #pragma unroll
        for (int kh = 0; kh < 2; kh++) {
            bf16_8 af[4], bfr[4];
            #pragma unroll
            for (int t = 0; t < 4; t++) {
                int ch = (kh * 4 + quad) ^ (lm & 7);
                af[t]  = *(const bf16_8*)&As[wm + t * 16 + lm][ch * 8];
                bfr[t] = *(const bf16_8*)&Bs[wn + t * 16 + lm][ch * 8];
            }
            #pragma unroll
            for (int i = 0; i < 4; i++)
                #pragma unroll
                for (int j = 0; j < 4; j++)
                    acc[i][j] = __builtin_amdgcn_mfma_f32_16x16x32_bf16(
                        af[i], bfr[j], acc[i][j], 0, 0, 0);
        }
    }

    float bvc[4];
    #pragma unroll
    for (int j = 0; j < 4; j++)
        bvc[j] = (z == 0) ? bias[n0 + wn + j * 16 + lm] : 0.f;

    #pragma unroll
    for (int i = 0; i < 4; i++)
        #pragma unroll
        for (int j = 0; j < 4; j++) {
            int col = n0 + wn + j * 16 + lm;
            #pragma unroll
            for (int r = 0; r < 4; r++) {
                int row = m0 + wm + i * 16 + quad * 4 + r;
                float v = acc[i][j][r] + bvc[j];
                if (RELU) v = fmaxf(v, 0.f);
                if (BF16OUT)
                    ((unsigned short*)Cz)[(size_t)row * ldc + col] = f2bf(v);
                else
                    ((float*)Cz)[(size_t)row * ldc + col] = v;
            }
        }
}

// ---------------------------------------------------------------------------
// FFN1 GEMM: hb[4096,4096] = relu(x1b[4096,1024] @ l1w[4096,1024]^T + l1_b).
// 256x128 tile, BK=64, LDS 48 KB, acc 4x8 per wave. 512 blocks = 2/CU exact.
// ---------------------------------------------------------------------------
__global__ __launch_bounds__(256, 2) void gemm_ffn1_kernel(
    const unsigned short* __restrict__ A, const unsigned short* __restrict__ W,
    const float* __restrict__ bias, unsigned short* __restrict__ C)
{
    __shared__ __bf16 As[256][64];   // 32 KB
    __shared__ __bf16 Bs[128][64];   // 16 KB
    const int tid  = threadIdx.x;
    const int lane = tid & 63;
    const int wave = tid >> 6;
    const int m0 = blockIdx.y * 256;
    const int n0 = blockIdx.x * 128;
    const int lr8 = lane >> 3;
    const int gch = (lane & 7) ^ lr8;
    const int quad = lane >> 4;
    const int lm = lane & 15;

    f32x4 acc[4][8];
    #pragma unroll
    for (int i = 0; i < 4; i++)
        #pragma unroll
        for (int j = 0; j < 8; j++) {
            acc[i][j][0] = 0.f; acc[i][j][1] = 0.f;
            acc[i][j][2] = 0.f; acc[i][j][3] = 0.f;
        }

    for (int k0 = 0; k0 < 1024; k0 += 64) {
        __syncthreads();
        #pragma unroll
        for (int i = 0; i < 8; i++) {          // A: 8 segments/wave
            int seg = wave * 8 + i;
            int r = seg * 8 + lr8;
            gld_lds16(A + (size_t)(m0 + r) * 1024 + k0 + gch * 8, &As[seg * 8][0]);
        }
        #pragma unroll
        for (int i = 0; i < 4; i++) {          // B: 4 segments/wave
            int seg = wave * 4 + i;
            int r = seg * 8 + lr8;
            gld_lds16(W + (size_t)(n0 + r) * 1024 + k0 + gch * 8, &Bs[seg * 8][0]);
        }
        __syncthreads();
        #pragma unroll
        for (int kh = 0; kh < 2; kh++) {
            const int ch = (kh * 4 + quad) ^ (lm & 7);
            bf16_8 af[4], bfr[8];
            #pragma unroll
            for (int t = 0; t < 4; t++)
                af[t] = *(const bf16_8*)&As[wave * 64 + t * 16 + lm][ch * 8];
            #pragma unroll
            for (int j = 0; j < 8; j++)
                bfr[j] = *(const bf16_8*)&Bs[j * 16 + lm][ch * 8];
            #pragma unroll
            for (int i = 0; i < 4; i++)
                #pragma unroll
                for (int j = 0; j < 8; j++)
                    acc[i][j] = __builtin_amdgcn_mfma_f32_16x16x32_bf16(
                        af[i], bfr[j], acc[i][j], 0, 0, 0);
        }
    }

    float bv[8];
    #pragma unroll
    for (int j = 0; j < 8; j++) bv[j] = bias[n0 + j * 16 + lm];

    #pragma unroll
    for (int i = 0; i < 4; i++)
        #pragma unroll
        for (int j = 0; j < 8; j++) {
            int col = n0 + j * 16 + lm;
            #pragma unroll
            for (int r = 0; r < 4; r++) {
                int row = m0 + wave * 64 + i * 16 + quad * 4 + r;
                float v = fmaxf(acc[i][j][r] + bv[j], 0.f);
                C[(size_t)row * Ff + col] = f2bf(v);
            }
        }
}

// ---------------------------------------------------------------------------
// Merged QK + Vt GEMM (768 blocks), BK=64.
// blocks [0,512):   qk16[4096,2048] = srcb @ [q_w;k_w]^T + qkb, Q cols ×ATT_C2
// blocks [512,768): vtf [1024,4096] = vw16 @ srcb^T + v_b (row bias)
// ---------------------------------------------------------------------------
__global__ __launch_bounds__(256) void gemm_qkvt_kernel(
    const unsigned short* __restrict__ srcb, const unsigned short* __restrict__ qkw,
    const unsigned short* __restrict__ vw16, const float* __restrict__ qkb,
    const float* __restrict__ v_b,
    unsigned short* __restrict__ qk16, unsigned short* __restrict__ vtf)
{
    const int bid = blockIdx.x;
    const unsigned short *A, *W;
    const float* bias;
    unsigned short* C;
    int m0, n0, ldc;
    bool qscale, rowbias;
    if (bid < 512) {
        A = srcb; W = qkw; bias = qkb; C = qk16;
        n0 = (bid & 15) * 128; m0 = (bid >> 4) * 128;
        ldc = 2048; qscale = true; rowbias = false;
    } else {
        int b2 = bid - 512;
        A = vw16; W = srcb; bias = v_b; C = vtf;
        n0 = (b2 & 31) * 128; m0 = (b2 >> 5) * 128;
        ldc = 4096; qscale = false; rowbias = true;
    }
    const int K = 1024;

    __shared__ __bf16 As[128][64];
    __shared__ __bf16 Bs[128][64];
    const int tid  = threadIdx.x;
    const int lane = tid & 63;
    const int wave = tid >> 6;
    const int lr8 = lane >> 3;
    const int gch = (lane & 7) ^ lr8;
    const int wm = (wave & 1) * 64;
    const int wn = (wave >> 1) * 64;
    const int quad = lane >> 4;
    const int lm = lane & 15;

    f32x4 acc[4][4];
    #pragma unroll
    for (int i = 0; i < 4; i++)
        #pragma unroll
        for (int j = 0; j < 4; j++) {
            acc[i][j][0] = 0.f; acc[i][j][1] = 0.f;
            acc[i][j][2] = 0.f; acc[i][j][3] = 0.f;
        }

    for (int k0 = 0; k0 < K; k0 += 64) {
        __syncthreads();
        #pragma unroll
        for (int i = 0; i < 4; i++) {
            int seg = wave * 4 + i;
            int r = seg * 8 + lr8;
            gld_lds16(A + (size_t)(m0 + r) * K + k0 + gch * 8, &As[seg * 8][0]);
            gld_lds16(W + (size_t)(n0 + r) * K + k0 + gch * 8, &Bs[seg * 8][0]);
        }
        __syncthreads();
        #pragma unroll
        for (int kh = 0; kh < 2; kh++) {
            bf16_8 af[4], bfr[4];
            #pragma unroll
            for (int t = 0; t < 4; t++) {
                int ch = (kh * 4 + quad) ^ (lm & 7);
                af[t]  = *(const bf16_8*)&As[wm + t * 16 + lm][ch * 8];
                bfr[t] = *(const bf16_8*)&Bs[wn + t * 16 + lm][ch * 8];
            }
            #pragma unroll
            for (int i = 0; i < 4; i++)
                #pragma unroll
                for (int j = 0; j < 4; j++)
                    acc[i][j] = __builtin_amdgcn_mfma_f32_16x16x32_bf16(
                        af[i], bfr[j], acc[i][j], 0, 0, 0);
        }
    }

    float bvc[4];
    float brr[4][4];
    if (!rowbias) {
        #pragma unroll
        for (int j = 0; j < 4; j++) bvc[j] = bias[n0 + wn + j * 16 + lm];
    } else {
        #pragma unroll
        for (int i = 0; i < 4; i++) {
            float4 t4 = *(const float4*)&bias[m0 + wm + i * 16 + quad * 4];
            brr[i][0] = t4.x; brr[i][1] = t4.y; brr[i][2] = t4.z; brr[i][3] = t4.w;
        }
    }

    #pragma unroll
    for (int i = 0; i < 4; i++)
        #pragma unroll
        for (int j = 0; j < 4; j++) {
            int col = n0 + wn + j * 16 + lm;
            #pragma unroll
            for (int r = 0; r < 4; r++) {
                int row = m0 + wm + i * 16 + quad * 4 + r;
                float v = acc[i][j][r] + (rowbias ? brr[i][r] : bvc[j]);
                if (qscale && col < 1024) v *= ATT_C2;
                C[(size_t)row * ldc + col] = f2bf(v);
            }
        }
}

// ---------------------------------------------------------------------------
// MFMA flash attention v3: 32x32x16 MFMA + in-register softmax repack.
// Round-1 post-mortem: 16x16 version was LDS-pipe-bound (~86%): Ps round-trip
// + per-wave K/V re-reads. This version:
//  - S^T via mfma_32x32x16(A=K, B=Q): P output is lane-local in t (col=lane&31)
//  - P -> PV A-frag entirely in registers: 8 cvt_pk + 4 permlane32_swap per
//    32-s block (HK T12 pairing pk(p[2i],p[2i+1]) with pk(p[2i+4],p[2i+5]))
//  - l row-sum = in-register adds (no ones-MFMA), one swap at end
//  - K/V double-buffered (66 KB LDS, 2 blocks/CU), 1 barrier/tile; stage(t+1)
//    issued after barrier so the vmcnt drain overlaps tile-t compute.
// Per wave-tile DS ops: 32 (was 44 with 2x waves) -> LDS floor ~49k cyc/CU.
// 4 waves x 32 t, grid (16, 32) = 2 blocks/CU.
// ---------------------------------------------------------------------------
__global__ __launch_bounds__(256) void attn_mfma_kernel(
    const unsigned short* __restrict__ qk,
    const unsigned short* __restrict__ vt,
    const unsigned* __restrict__ mb,
    unsigned short* __restrict__ out)
{
    __shared__ __bf16 Ks[2][128 * 64];   // 2 x 16 KB
    __shared__ __bf16 Vt[2][64 * 128];   // 2 x 16 KB
    __shared__ float  l_s[128];          // per-t 1/l for epilogue

    const int tid  = threadIdx.x;
    const int lane = tid & 63;
    const int wave = tid >> 6;           // 0..3
    const int l31  = lane & 31;
    const int hi   = lane >> 5;
    const int x7   = l31 & 7;
    const int bh = blockIdx.y;
    const int b = bh >> 4, h = bh & 15;
    const int tw = blockIdx.x * 128 + wave * 32;

    // Q B-frags: B[k=hi*8+j][col=t=l31], 4 dsteps of 16 covering d=0..63
    bf16_8 qf[4];
    #pragma unroll
    for (int ds4 = 0; ds4 < 4; ++ds4)
        qf[ds4] = *(const bf16_8*)(qk +
            (size_t)(b * Tt + tw + l31) * 2048 + h * DHd + ds4 * 16 + hi * 8);

    f32x16 oacc[2];
    #pragma unroll
    for (int d = 0; d < 2; ++d)
        #pragma unroll
        for (int r = 0; r < 16; ++r) oacc[d][r] = 0.f;
    float lsum = 0.f;

    const int krow8 = lane >> 3;
    const int kj    = (lane & 7) ^ krow8;    // K staging swizzle
    const int vr4   = lane >> 4;

    auto STAGE = [&](int nb, int s0) {
        #pragma unroll
        for (int i = 0; i < 4; ++i) {
            int ci = wave * 4 + i;           // 0..15
            {
                int r = 8 * ci + krow8;
                const unsigned short* g = qk +
                    (size_t)(b * Tt + s0 + r) * 2048 + 1024 + h * DHd + kj * 8;
                gld_lds16(g, &Ks[nb][ci * 512]);
            }
            {
                int d = 4 * ci + vr4;
                int jj = (lane & 15) ^ (d & 7);
                const unsigned short* g = vt +
                    (size_t)(h * DHd + d) * 4096 + b * Tt + s0 + jj * 8;
                gld_lds16(g, &Vt[nb][ci * 512]);
            }
        }
    };

    STAGE(0, 0);

    for (int st = 0; st < 16; ++st) {
        const int cb = st & 1;
        const int s0 = st * 128;
        __syncthreads();                     // buf[cb] staged; all waves done with buf[cb^1]

        // mask words first (their wait is vmcnt(8), not a full drain)
        unsigned mwv[4];
        #pragma unroll
        for (int sb = 0; sb < 4; ++sb)
            mwv[sb] = mb[(size_t)(tw + l31) * 64 + (s0 >> 5) + sb];

        if (st < 15) STAGE(cb ^ 1, s0 + 128);

        #pragma unroll
        for (int sb = 0; sb < 4; ++sb) {
            // ---- S^T: 32 s x 32 t, K streamed from LDS, Q in regs ----
            f32x16 sacc;
            #pragma unroll
            for (int r = 0; r < 16; ++r) sacc[r] = 0.f;
            #pragma unroll
            for (int ds4 = 0; ds4 < 4; ++ds4) {
                bf16_8 kf = *(const bf16_8*)&Ks[cb][
                    (sb * 32 + l31) * 64 + (((ds4 * 2 + hi) ^ x7) * 8)];
                sacc = __builtin_amdgcn_mfma_f32_32x32x16_bf16(
                    kf, qf[ds4], sacc, 0, 0, 0);
            }
            // ---- mask + exp2 + row-sum (lane-local: col=t=l31) ----
            const unsigned mword = mwv[sb];
            float p[16];
            #pragma unroll
            for (int g = 0; g < 4; ++g)
                #pragma unroll
                for (int m = 0; m < 4; ++m) {
                    const int reg = g * 4 + m;
                    const int srow = m + 8 * g + 4 * hi;   // s within 32-block
                    float x = ((mword >> srow) & 1u) ? -1e30f : sacc[reg];
                    float e = __builtin_amdgcn_exp2f(x);
                    p[reg] = e;
                    lsum += e;
                }
            // ---- in-register repack to PV A-frags (T12) ----
            unsigned u[4], v[4];
            #pragma unroll
            for (int g = 0; g < 4; ++g) {
                u[g] = __builtin_bit_cast(unsigned, pkbf(p[g * 4 + 0], p[g * 4 + 1]));
                v[g] = __builtin_bit_cast(unsigned, pkbf(p[g * 4 + 2], p[g * 4 + 3]));
            }
            plswap32(u[0], u[1]); plswap32(v[0], v[1]);   // kstep0: s 0..15
            plswap32(u[2], u[3]); plswap32(v[2], v[3]);   // kstep1: s 16..31
            u32x4 w0; w0[0] = u[0]; w0[1] = v[0]; w0[2] = u[1]; w0[3] = v[1];
            u32x4 w1; w1[0] = u[2]; w1[1] = v[2]; w1[2] = u[3]; w1[3] = v[3];
            bf16_8 pa0 = __builtin_bit_cast(bf16_8, w0);
            bf16_8 pa1 = __builtin_bit_cast(bf16_8, w1);
            // ---- PV: O[t][d] += P V, V streamed from LDS ----
            #pragma unroll
            for (int kst = 0; kst < 2; ++kst) {
                bf16_8 pa = kst ? pa1 : pa0;
                #pragma unroll
                for (int dblk = 0; dblk < 2; ++dblk) {
                    int cpos = (sb * 4 + kst * 2 + hi) ^ x7;
                    bf16_8 vf = *(const bf16_8*)&Vt[cb][
                        ((dblk * 32 + l31) * 16 + cpos) * 8];
                    oacc[dblk] = __builtin_amdgcn_mfma_f32_32x32x16_bf16(
                        pa, vf, oacc[dblk], 0, 0, 0);
                }
            }
        }
    }

    // ---- l: combine hi/lo halves, redistribute t=l31 -> O row layout ----
    unsigned la = __builtin_bit_cast(unsigned, lsum), lb = la;
    plswap32(la, lb);
    float ltot = __builtin_bit_cast(float, la) + __builtin_bit_cast(float, lb);
    l_s[wave * 32 + l31] = (ltot > 0.f) ? 1.f / ltot : 0.f;
    __syncthreads();

    #pragma unroll
    for (int g = 0; g < 4; ++g)
        #pragma unroll
        for (int m = 0; m < 4; ++m) {
            const int reg = g * 4 + m;
            const int tr = m + 8 * g + 4 * hi;      // row within 32-block
            float inv = l_s[wave * 32 + tr];
            int row = b * Tt + tw + tr;
            #pragma unroll
            for (int dblk = 0; dblk < 2; ++dblk)
                out[(size_t)row * Dm + h * DHd + dblk * 32 + l31] =
                    f2bf(oacc[dblk][reg] * inv);
        }
}

// ---------------------------------------------------------------------------
// out = LayerNorm(base + alpha*(d0[+d1]))*scale + bias.
// BASEBF: base is bf16. OUTF32 -> out fp32; OUTBF -> out_bf bf16.
// ---------------------------------------------------------------------------
template<int NPARTS, int BASEBF, int OUTF32, int OUTBF>
__global__ __launch_bounds__(256) void residual_ln_kernel(
    const void* __restrict__ base, const float* __restrict__ d0,
    const float* __restrict__ d1,
    const float* __restrict__ alpha_p, const float* __restrict__ scale,
    const float* __restrict__ bias, float* __restrict__ out,
    unsigned short* __restrict__ out_bf)
{
    const int row = blockIdx.x;
    const int tid = threadIdx.x;
    const float alpha = alpha_p[0];
    float4 xb;
    if (BASEBF) {
        bf16x4 bb = ((const bf16x4*)((const unsigned short*)base + (size_t)row * Dm))[tid];
        xb.x = (float)bb[0]; xb.y = (float)bb[1]; xb.z = (float)bb[2]; xb.w = (float)bb[3];
    } else {
        xb = ((const float4*)((const float*)base + (size_t)row * Dm))[tid];
    }
    float4 xd = ((const float4*)(d0 + (size_t)row * Dm))[tid];
    if (NPARTS == 2) {
        float4 x2 = ((const float4*)(d1 + (size_t)row * Dm))[tid];
        xd.x += x2.x; xd.y += x2.y; xd.z += x2.z; xd.w += x2.w;
    }
    float4 x;
    x.x = xb.x + alpha * xd.x;
    x.y = xb.y + alpha * xd.y;
    x.z = xb.z + alpha * xd.z;
    x.w = xb.w + alpha * xd.w;
    float s  = x.x + x.y + x.z + x.w;
    float sq = x.x*x.x + x.y*x.y + x.z*x.z + x.w*x.w;
    #pragma unroll
    for (int off = 32; off > 0; off >>= 1) {
        s  += __shfl_down(s, off, 64);
        sq += __shfl_down(sq, off, 64);
    }
    __shared__ float red[8];
    const int w = tid >> 6;
    if ((tid & 63) == 0) { red[w] = s; red[4 + w] = sq; }
    __syncthreads();
    s  = red[0] + red[1] + red[2] + red[3];
    sq = red[4] + red[5] + red[6] + red[7];
    const float mu  = s * (1.f / Dm);
    const float var = sq * (1.f / Dm) - mu * mu;
    const float r   = rsqrtf(var + 1e-5f);
    float4 sc = ((const float4*)scale)[tid];
    float4 bi = ((const float4*)bias)[tid];
    float4 o;
    o.x = (x.x - mu) * r * sc.x + bi.x;
    o.y = (x.y - mu) * r * sc.y + bi.y;
    o.z = (x.z - mu) * r * sc.z + bi.z;
    o.w = (x.w - mu) * r * sc.w + bi.w;
    if (OUTF32)
        ((float4*)(out + (size_t)row * Dm))[tid] = o;
    if (OUTBF)
        ((bf16x4*)(out_bf + (size_t)row * Dm))[tid] = pkbf4(o.x, o.y, o.z, o.w);
}

// ---------------------------------------------------------------------------
extern "C" void kernel_launch(void* const* d_in, const int* in_sizes, int n_in,
                              void* d_out, int out_size, void* d_ws, size_t ws_size,
                              hipStream_t stream)
{
    (void)in_sizes; (void)n_in; (void)out_size; (void)ws_size;
    const float* src  = (const float*)d_in[0];
    const int*   mask = (const int*)  d_in[1];
    const float* q_w  = (const float*)d_in[2];
    const float* q_b  = (const float*)d_in[3];
    const float* k_w  = (const float*)d_in[4];
    const float* k_b  = (const float*)d_in[5];
    const float* v_w  = (const float*)d_in[6];
    const float* v_b  = (const float*)d_in[7];
    const float* o_w  = (const float*)d_in[8];
    const float* o_b  = (const float*)d_in[9];
    const float* l1_w = (const float*)d_in[10];
    const float* l1_b = (const float*)d_in[11];
    const float* l2_w = (const float*)d_in[12];
    const float* l2_b = (const float*)d_in[13];
    const float* n1_s = (const float*)d_in[14];
    const float* n1_b = (const float*)d_in[15];
    const float* n2_s = (const float*)d_in[16];
    const float* n2_b = (const float*)d_in[17];
    const float* a_attn = (const float*)d_in[18];
    const float* a_ff   = (const float*)d_in[19];

    // ---- workspace layout (96 MB), lifetimes annotated ----
    const size_t MB = 1024 * 1024;
    char* w = (char*)d_ws;
    unsigned short* qkw  = (unsigned short*)(w + 0);        // [ 0, 4)   -> qkvt
    unsigned short* vw16 = (unsigned short*)(w + 4  * MB);  // [ 4, 6)   -> qkvt
    unsigned short* ow   = (unsigned short*)(w + 6  * MB);  // [ 6, 8)   -> O gemm
    unsigned short* l1w  = (unsigned short*)(w + 8  * MB);  // [ 8,16)   -> FFN1
    unsigned short* l2w  = (unsigned short*)(w + 16 * MB);  // [16,24)   -> FFN2
    unsigned short* srcb = (unsigned short*)(w + 24 * MB);  // [24,32)   -> qkvt
    unsigned short* qk16 = (unsigned short*)(w + 32 * MB);  // [32,48)   -> attn
    unsigned short* vtf  = (unsigned short*)(w + 48 * MB);  // [48,56)   -> attn
    unsigned*       mbit = (unsigned*)      (w + 56 * MB);            // 512 KB
    float*          qkb  = (float*)         (w + 56 * MB + 524288);   // 8 KB
    // post-attention reuse:
    unsigned short* atb  = (unsigned short*)(w + 24 * MB);  // [24,32)   -> O gemm (srcb dead)
    float*          o0   = (float*)         (w + 58 * MB);  // [58,74)   -> LN1
    float*          o1   = (float*)         (w + 74 * MB);  // [74,90)   -> LN1
    unsigned short* x1b  = (unsigned short*)(w + 48 * MB);  // [48,56)   -> FFN1+LN2 (vtf dead)
    unsigned short* hb   = (unsigned short*)(w + 58 * MB);  // [58,90)   -> FFN2 (o0/o1 dead)
    float*          fp0  = (float*)         (w + 0);        // [ 0,16)   -> LN2 (qkw/vw16/ow dead)
    float*          fp1  = (float*)         (w + 32 * MB);  // [32,48)   -> LN2 (qk16 dead)

    const int MR = Bb * Tt;   // 4096
    dim3 blk(256);

    // 1) conversions + mask pack + bias concat
    preprocess_kernel<<<dim3(16904), blk, 0, stream>>>(
        q_w, k_w, v_w, o_w, l1_w, l2_w, src, mask, q_b, k_b,
        qkw, vw16, ow, l1w, l2w, srcb, mbit, qkb);
    // 2) merged QK + Vt GEMMs
    gemm_qkvt_kernel<<<dim3(768), blk, 0, stream>>>(
        srcb, qkw, vw16, qkb, v_b, qk16, vtf);
    // 3) MFMA flash attention -> atb bf16 (single dispatch, full s sweep)
    attn_mfma_kernel<<<dim3(16, 32), blk, 0, stream>>>(qk16, vtf, mbit, atb);
    // 4) O projection, split-K=2 -> two fp32 partials
    gemm_bf16_kernel<0, 0><<<dim3(8, 32, 2), blk, 0, stream>>>(
        atb, ow, o_b, o0, o1, MR, Dm, Dm, Dm, 512);
    // 5) LN1 (sums O partials) -> x1b bf16 only
    residual_ln_kernel<2, 0, 0, 1><<<dim3(MR), blk, 0, stream>>>(
        src, o0, o1, a_attn, n1_s, n1_b, nullptr, x1b);
    // 6) FFN1 + ReLU -> bf16 hidden, 256x128 tile
    gemm_ffn1_kernel<<<dim3(32, 16), blk, 0, stream>>>(x1b, l1w, l1_b, hb);
    // 7) FFN2, split-K=2 -> two fp32 partials
    gemm_bf16_kernel<0, 0><<<dim3(8, 32, 2), blk, 0, stream>>>(
        hb, l2w, l2_b, fp0, fp1, MR, Dm, Ff, Dm, Ff / 2);
    // 8) LN2 (bf16 base x1b; sums FFN2 partials) -> final fp32 output
    residual_ln_kernel<2, 1, 1, 0><<<dim3(MR), blk, 0, stream>>>(
        x1b, fp0, fp1, a_ff, n2_s, n2_b, (float*)d_out, nullptr);
}